// Round 10
// baseline (182.827 us; speedup 1.0000x reference)
//
#include <hip/hip_runtime.h>

#define B_N 256
#define IC_N 1152
#define J_N 10
#define D_N 16

typedef __attribute__((ext_vector_type(8))) short short8;
typedef __attribute__((ext_vector_type(4))) float floatx4;

union u4s8 { uint4 u; short8 s; };

__device__ __forceinline__ float bf_lo(unsigned int u){
  union { unsigned int i; float f; } c; c.i = u << 16; return c.f;
}
__device__ __forceinline__ float bf_hi(unsigned int u){
  union { unsigned int i; float f; } c; c.i = u & 0xffff0000u; return c.f;
}
__device__ __forceinline__ unsigned int rne16(float f){
  union { float ff; unsigned int i; } c; c.ff = f;
  return (c.i + 0x7FFFu + ((c.i >> 16) & 1u)) >> 16;
}
__device__ __forceinline__ unsigned int pack_rne(float lo, float hi){
  return rne16(lo) | (rne16(hi) << 16);
}
__device__ __forceinline__ unsigned int pack_trunc(float lo, float hi){
  union { float f; unsigned int u; } a, b; a.f = lo; b.f = hi;
  return __builtin_amdgcn_perm(b.u, a.u, 0x07060302u);
}

// prep: identical to the verified R0/R3/R5 kernel (layouts R5..R13).
__global__ __launch_bounds__(256) void caps_prep(
    const float* __restrict__ W, uint4* __restrict__ wsf,
    uint4* __restrict__ wcc2, float* __restrict__ vsum)
{
  const int tid = threadIdx.x;
  const int t0 = blockIdx.x * 256 + tid;
  if (t0 < B_N * J_N * D_N) vsum[t0] = 0.f;
  __shared__ unsigned int lw[1024];
  const int j = blockIdx.x / 72, itile = blockIdx.x % 72;
  const float4* Wt = (const float4*)(W + ((size_t)(j * IC_N + itile * 16) << 7));
  #pragma unroll
  for (int h = 0; h < 2; ++h) {
    const float4 f = Wt[h * 256 + tid];
    lw[(h * 256 + tid) * 2]     = pack_rne(f.x, f.y);
    lw[(h * 256 + tid) * 2 + 1] = pack_rne(f.z, f.w);
  }
  __syncthreads();
  {  // wsf emit
    const int ktl = tid >> 6, ln = tid & 63;
    const int base = (ktl * 4 + (ln >> 4)) * 64 + (ln & 15) * 4;
    uint4 q;
    q.x = lw[base]; q.y = lw[base + 1]; q.z = lw[base + 2]; q.w = lw[base + 3];
    wsf[((size_t)j * 288 + itile * 4 + ktl) * 64 + ln] = q;
  }
  {  // wcc2 emit
    const int e = tid >> 5, lane2 = tid & 31;
    const int il = lane2 & 15, dbase = (lane2 >> 4) * 8;
    unsigned short h[8];
    #pragma unroll
    for (int k = 0; k < 8; ++k) {
      const unsigned int u = lw[il * 64 + (dbase + k) * 4 + (e >> 1)];
      h[k] = (e & 1) ? (unsigned short)(u >> 16) : (unsigned short)(u & 0xffffu);
    }
    uint4 q;
    q.x = h[0] | ((unsigned int)h[1] << 16);
    q.y = h[2] | ((unsigned int)h[3] << 16);
    q.z = h[4] | ((unsigned int)h[5] << 16);
    q.w = h[6] | ((unsigned int)h[7] << 16);
    wcc2[(((size_t)j * 8 + e) * 72 + itile) * 32 + lane2] = q;
  }
}

// Pass R10: ONE WAVE per (btile, 16-i chunk); j 0..9 handled SERIALLY in
// the wave. Rationale (R8 probe + R5/R6/R9 nulls): the 10-wave block only
// parallelized j, at the price of 3 cross-wave barriers per chunk whose
// vmcnt(0) drains convoy all loads. One wave = zero cross-wave barriers;
// softmax over j is per-lane register math (cc[j] of one (b,i) cell lives
// in one lane); the fully-unrolled j-loop exposes 120 loads to pipeline
// under 120 MFMAs. MFMA fragments / indices / rounding are the verified
// R0 16-i bodies verbatim with wave -> j.
__global__ __launch_bounds__(64, 3) void caps_pass(
    const float* __restrict__ x,
    const uint4* __restrict__ wsf, const uint4* __restrict__ wcc2,
    const uint4* __restrict__ vsbf, float* __restrict__ s_part, const int round)
{
  __shared__ float ccl[10 * 16 * 17];      // [j][i][b pad17] 10.9 KB
  __shared__ unsigned int xt[16 * 17 * 4]; // [i][b pad17] uint4 4.3 KB

  const int lane = threadIdx.x;            // 64
  const int quad = lane >> 4;
  const int col  = lane & 15;

  // XCD swizzle: 1152 = 8 xcd * 144; same-by blocks (W-sharing) colocate.
  const int bid = blockIdx.x;
  const int wid = (bid & 7) * 144 + (bid >> 3);
  const int bx  = wid & 15;                // btile
  const int by  = wid >> 4;                // i-chunk 0..71 (16 i)
  const int b0  = bx << 4;
  const int i0  = by << 4;

  // ---- stage x tile [16i][16b pad17] (R0 values: same pack_rne) ----
  #pragma unroll
  for (int t = 0; t < 8; ++t) {
    const int idx = t * 64 + lane;
    const int b = idx >> 5, i4 = idx & 31;
    const int i = i4 >> 1, half = i4 & 1;
    const float4 v = ((const float4*)(x + ((size_t)((b0 + b) * IC_N + i0 + i) << 3)))[half];
    const int o = ((i * 17 + b) << 2) + (half << 1);
    xt[o]     = pack_rne(v.x, v.y);
    xt[o + 1] = pack_rne(v.z, v.w);
  }
  __syncthreads();                         // 1-wave block: cheap waitcnt
  const uint4* xtq = (const uint4*)xt;

  if (round > 0) {
    // ---- phase A: cc[j] for all 10 j, accumulated in registers ----
    uint4 xr[4];                           // x[b=quad*4+r][i=col]
    #pragma unroll
    for (int r = 0; r < 4; ++r)
      xr[r] = xtq[col * 17 + quad * 4 + r];
    floatx4 cc4[10];
    #pragma unroll
    for (int j = 0; j < 10; ++j) {
      short8 av = {0,0,0,0,0,0,0,0};       // v[b=col][d]; quad 2,3 zero-pad
      if (quad < 2)
        av = *(const short8*)&vsbf[((size_t)(b0 + col) * J_N + j) * 2 + quad];
      floatx4 c4 = {0.f, 0.f, 0.f, 0.f};
      #pragma unroll
      for (int e = 0; e < 8; ++e) {
        uint4 q = {0u, 0u, 0u, 0u};
        if (lane < 32)
          q = wcc2[(((size_t)j * 8 + e) * 72 + by) * 32 + lane];
        u4s8 bv; bv.u = q;
        floatx4 tf = {0.f, 0.f, 0.f, 0.f};
        tf = __builtin_amdgcn_mfma_f32_16x16x32_bf16(av, bv.s, tf, 0, 0, 0);
        #pragma unroll
        for (int r = 0; r < 4; ++r) {
          const unsigned int u = ((const unsigned int*)&xr[r])[e >> 1];
          const float xe = (e & 1) ? bf_hi(u) : bf_lo(u);
          c4[r] += tf[r] * xe;
        }
      }
      cc4[j] = c4;
    }
    // ---- softmax over j: pure per-lane register math (no barrier) ----
    #pragma unroll
    for (int r = 0; r < 4; ++r) {
      float m = cc4[0][r];
      #pragma unroll
      for (int j = 1; j < 10; ++j) m = fmaxf(m, cc4[j][r]);
      float e10[10];
      float den = 0.f;
      #pragma unroll
      for (int j = 0; j < 10; ++j) { e10[j] = __expf(cc4[j][r] - m); den += e10[j]; }
      const float rd = __builtin_amdgcn_rcpf(den);
      #pragma unroll
      for (int j = 0; j < 10; ++j)         // lane transpose i<->b via LDS
        ccl[(j * 16 + col) * 17 + quad * 4 + r] = e10[j] * rd;
    }
    __syncthreads();                       // 1-wave: waitcnt only
  }

  // ---- phase B: s[b,d] += (c*x) @ Ws, K=128 per j (R0 4-kt chain) ----
  uint4 xq[4];                             // x[i=kt*4+quad][b=col], j-invariant
  #pragma unroll
  for (int kt = 0; kt < 4; ++kt)
    xq[kt] = xtq[(kt * 4 + quad) * 17 + col];

  if (round == 0) {
    short8 af4[4];                         // c = 0.1 for all j: hoist packs
    #pragma unroll
    for (int kt = 0; kt < 4; ++kt) {
      unsigned int* aq = (unsigned int*)&af4[kt];
      const uint4 q = xq[kt];
      aq[0] = pack_trunc(bf_lo(q.x) * 0.1f, bf_hi(q.x) * 0.1f);
      aq[1] = pack_trunc(bf_lo(q.y) * 0.1f, bf_hi(q.y) * 0.1f);
      aq[2] = pack_trunc(bf_lo(q.z) * 0.1f, bf_hi(q.z) * 0.1f);
      aq[3] = pack_trunc(bf_lo(q.w) * 0.1f, bf_hi(q.w) * 0.1f);
    }
    #pragma unroll
    for (int j = 0; j < 10; ++j) {
      floatx4 acc = {0.f, 0.f, 0.f, 0.f};
      #pragma unroll
      for (int kt = 0; kt < 4; ++kt) {
        u4s8 bw; bw.u = wsf[((size_t)j * 288 + (by << 2) + kt) * 64 + lane];
        acc = __builtin_amdgcn_mfma_f32_16x16x32_bf16(af4[kt], bw.s, acc, 0, 0, 0);
      }
      float* sp = s_part + ((((size_t)bx * 10 + j) * 16 + quad * 4) * 72 + by) * 16 + col;
      #pragma unroll
      for (int r = 0; r < 4; ++r) sp[(size_t)r * 72 * 16] = acc[r];
    }
  } else {
    #pragma unroll
    for (int j = 0; j < 10; ++j) {
      floatx4 acc = {0.f, 0.f, 0.f, 0.f};
      #pragma unroll
      for (int kt = 0; kt < 4; ++kt) {
        const float c = ccl[(j * 16 + (kt * 4 + quad)) * 17 + col];
        const uint4 q = xq[kt];
        short8 af;
        unsigned int* aq = (unsigned int*)&af;
        aq[0] = pack_trunc(bf_lo(q.x) * c, bf_hi(q.x) * c);
        aq[1] = pack_trunc(bf_lo(q.y) * c, bf_hi(q.y) * c);
        aq[2] = pack_trunc(bf_lo(q.z) * c, bf_hi(q.z) * c);
        aq[3] = pack_trunc(bf_lo(q.w) * c, bf_hi(q.w) * c);
        u4s8 bw; bw.u = wsf[((size_t)j * 288 + (by << 2) + kt) * 64 + lane];
        acc = __builtin_amdgcn_mfma_f32_16x16x32_bf16(af, bw.s, acc, 0, 0, 0);
      }
      float* sp = s_part + ((((size_t)bx * 10 + j) * 16 + quad * 4) * 72 + by) * 16 + col;
      #pragma unroll
      for (int r = 0; r < 4; ++r) sp[(size_t)r * 72 * 16] = acc[r];
    }
  }
}

// squash: verified R0 version (72 chunks, 18 coalesced loads).
__global__ __launch_bounds__(256) void caps_squash(
    const float* __restrict__ s_part, float* __restrict__ vsum,
    unsigned int* __restrict__ vsbf_u, float* __restrict__ out, const int round)
{
  const int tid  = threadIdx.x;
  const int w    = tid >> 6;
  const int lane = tid & 63;
  const int bj   = blockIdx.x * 4 + w;
  const int b    = bj / 10, j = bj - b * 10;
  const int btile = b >> 4, brem = b & 15;
  const float* base = s_part + (((size_t)btile * 10 + j) * 16 + brem) * 1152;
  float acc = 0.f;
  #pragma unroll
  for (int q = 0; q < 18; ++q) acc += base[q * 64 + lane];
  acc += __shfl_xor(acc, 16, 64);
  acc += __shfl_xor(acc, 32, 64);
  const float s = acc;
  float sq = s * s;
  sq += __shfl_xor(sq, 1, 16);
  sq += __shfl_xor(sq, 2, 16);
  sq += __shfl_xor(sq, 4, 16);
  sq += __shfl_xor(sq, 8, 16);
  const float coef = (sq / (1.f + sq)) * rsqrtf(sq + 1e-7f);
  const float v = coef * s;
  if (round < 2) {
    const float vprev = (lane < 16) ? vsum[bj * 16 + lane] : 0.f;
    const float vt = vprev + v;
    const float vtn = __shfl_down(vt, 1, 64);
    if (lane < 16) {
      vsum[bj * 16 + lane] = vt;
      if (!(lane & 1))
        vsbf_u[bj * 8 + (lane >> 1)] = pack_rne(vt, vtn);
    }
  } else if (lane < 16) {
    out[bj * 16 + lane] = v;
  }
}

extern "C" void kernel_launch(void* const* d_in, const int* in_sizes, int n_in,
                              void* d_out, int out_size, void* d_ws, size_t ws_size,
                              hipStream_t stream)
{
  const float* x_p = (const float*)d_in[0];   // [256][1152][8] fp32
  const float* W_p = (const float*)d_in[1];   // [10][1152][16][8] fp32

  uint4* wsf   = (uint4*)d_ws;
  uint4* wcc2  = wsf + 184320;
  float* s_prt = (float*)(wcc2 + 184320);             // 2949120 f (72-chunk)
  float* vsum  = s_prt + 2949120;                     // 40960 f
  unsigned int* vsbf_u = (unsigned int*)(vsum + 40960);
  float* out_p = (float*)d_out;

  caps_prep<<<dim3(720), dim3(256), 0, stream>>>(W_p, wsf, wcc2, vsum);
  for (int r = 0; r < 3; ++r) {
    caps_pass<<<dim3(1152), dim3(64), 0, stream>>>(
        x_p, wsf, wcc2, (const uint4*)vsbf_u, s_prt, r);
    caps_squash<<<dim3(640), dim3(256), 0, stream>>>(
        s_prt, vsum, vsbf_u, out_p, r);
  }
}

// Round 11
// 111.453 us; speedup vs baseline: 1.6404x; 1.6404x over previous
//
#include <hip/hip_runtime.h>

#define B_N 256
#define IC_N 1152
#define J_N 10
#define D_N 16

typedef __attribute__((ext_vector_type(8))) short short8;
typedef __attribute__((ext_vector_type(4))) float floatx4;

union u4s8 { uint4 u; short8 s; };

__device__ __forceinline__ float bf_lo(unsigned int u){
  union { unsigned int i; float f; } c; c.i = u << 16; return c.f;
}
__device__ __forceinline__ float bf_hi(unsigned int u){
  union { unsigned int i; float f; } c; c.i = u & 0xffff0000u; return c.f;
}
__device__ __forceinline__ unsigned int rne16(float f){
  union { float ff; unsigned int i; } c; c.ff = f;
  return (c.i + 0x7FFFu + ((c.i >> 16) & 1u)) >> 16;
}
__device__ __forceinline__ unsigned int pack_rne(float lo, float hi){
  return rne16(lo) | (rne16(hi) << 16);
}
__device__ __forceinline__ unsigned int pack_trunc(float lo, float hi){
  union { float f; unsigned int u; } a, b; a.f = lo; b.f = hi;
  return __builtin_amdgcn_perm(b.u, a.u, 0x07060302u);
}

// prep: verified W emits (R5..R13) + x -> bf16 xbf pack (same pack_rne bits
// as the old in-pass staging -> values bit-identical downstream).
__global__ __launch_bounds__(256) void caps_prep(
    const float* __restrict__ W, const float* __restrict__ x,
    uint4* __restrict__ wsf, uint4* __restrict__ wcc2,
    float* __restrict__ vsum, unsigned int* __restrict__ xbf)
{
  const int tid = threadIdx.x;
  const int t0 = blockIdx.x * 256 + tid;
  if (t0 < B_N * J_N * D_N) vsum[t0] = 0.f;
  // x pack: 1179648 uints, grid-strided, coalesced float2 reads
  for (int g = t0; g < B_N * IC_N * 4; g += 720 * 256) {
    const float2 f = ((const float2*)x)[g];
    xbf[g] = pack_rne(f.x, f.y);
  }
  __shared__ unsigned int lw[1024];
  const int j = blockIdx.x / 72, itile = blockIdx.x % 72;
  const float4* Wt = (const float4*)(W + ((size_t)(j * IC_N + itile * 16) << 7));
  #pragma unroll
  for (int h = 0; h < 2; ++h) {
    const float4 f = Wt[h * 256 + tid];
    lw[(h * 256 + tid) * 2]     = pack_rne(f.x, f.y);
    lw[(h * 256 + tid) * 2 + 1] = pack_rne(f.z, f.w);
  }
  __syncthreads();
  {  // wsf emit
    const int ktl = tid >> 6, ln = tid & 63;
    const int base = (ktl * 4 + (ln >> 4)) * 64 + (ln & 15) * 4;
    uint4 q;
    q.x = lw[base]; q.y = lw[base + 1]; q.z = lw[base + 2]; q.w = lw[base + 3];
    wsf[((size_t)j * 288 + itile * 4 + ktl) * 64 + ln] = q;
  }
  {  // wcc2 emit
    const int e = tid >> 5, lane2 = tid & 31;
    const int il = lane2 & 15, dbase = (lane2 >> 4) * 8;
    unsigned short h[8];
    #pragma unroll
    for (int k = 0; k < 8; ++k) {
      const unsigned int u = lw[il * 64 + (dbase + k) * 4 + (e >> 1)];
      h[k] = (e & 1) ? (unsigned short)(u >> 16) : (unsigned short)(u & 0xffffu);
    }
    uint4 q;
    q.x = h[0] | ((unsigned int)h[1] << 16);
    q.y = h[2] | ((unsigned int)h[3] << 16);
    q.z = h[4] | ((unsigned int)h[5] << 16);
    q.w = h[6] | ((unsigned int)h[7] << 16);
    wcc2[(((size_t)j * 8 + e) * 72 + itile) * 32 + lane2] = q;
  }
}

// Pass: EXACT R5 backbone (best known, 110.2us). ONLY change vs R5:
// stage reads pre-packed xbf (1 uint4 load + 1 uint4 LDS store, no pack)
// -> halves the per-pass x refetch (largest L2-miss component) and drops
// a dependent VALU step from the stage critical path. Single-variable A/B.
__global__ __launch_bounds__(640, 5) void caps_pass(
    const unsigned int* __restrict__ xbf,
    const uint4* __restrict__ wsf, const uint4* __restrict__ wcc2,
    const uint4* __restrict__ vsbf, float* __restrict__ s_part, const int round)
{
  __shared__ float ccl[10 * 32 * 17];     // 21.8 KB
  __shared__ unsigned int xt[32 * 17 * 4];// [i 0..31][b pad17] uint4, 8.7 KB

  const int tid  = threadIdx.x;
  const int wave = tid >> 6;              // = j
  const int lane = tid & 63;
  const int quad = lane >> 4;
  const int col  = lane & 15;

  // XCD swizzle (R5): 576 blocks = 8 xcd * 72; contiguous work per XCD.
  const int bid = blockIdx.x;
  const int wid = (bid & 7) * 72 + (bid >> 3);
  const int bx  = wid & 15;               // btile
  const int by  = wid >> 4;               // i-chunk 0..35
  const int b0  = bx << 4;
  const int i0  = by << 5;                // 32 i per block

  // ---- stage x tile from xbf: 512 threads, one uint4 each ----
  if (tid < 512) {
    const int b = tid >> 5, i = tid & 31;
    ((uint4*)xt)[i * 17 + b] =
        ((const uint4*)xbf)[(size_t)(b0 + b) * IC_N + i0 + i];
  }

  uint4 wf8[8];
  if (round == 0) {
    #pragma unroll
    for (int kt = 0; kt < 8; ++kt)
      wf8[kt] = wsf[((size_t)wave * 288 + (by << 3) + kt) * 64 + lane];
  }
  __syncthreads();
  const uint4* xtq = (const uint4*)xt;

  if (round > 0) {
    short8 av = {0,0,0,0,0,0,0,0};        // vsum[b=col][d=quad*8+..]; q2,3 pad
    if (quad < 2)
      av = *(const short8*)&vsbf[((size_t)(b0 + col) * J_N + wave) * 2 + quad];
    #pragma unroll
    for (int c = 0; c < 2; ++c) {         // two 16-i chunks, sequential
      uint4 bvq[8];
      #pragma unroll
      for (int e = 0; e < 8; ++e) {
        uint4 q = {0u, 0u, 0u, 0u};
        if (lane < 32)
          q = wcc2[(((size_t)wave * 8 + e) * 72 + (by * 2 + c)) * 32 + lane];
        bvq[e] = q;
      }
      uint4 xr[4];                        // x[b=quad*4+r][i=c*16+col]
      #pragma unroll
      for (int r = 0; r < 4; ++r)
        xr[r] = xtq[(c * 16 + col) * 17 + quad * 4 + r];
      floatx4 cc4 = {0.f, 0.f, 0.f, 0.f};
      #pragma unroll
      for (int e = 0; e < 8; ++e) {
        u4s8 bv; bv.u = bvq[e];
        floatx4 tf = {0.f, 0.f, 0.f, 0.f};
        tf = __builtin_amdgcn_mfma_f32_16x16x32_bf16(av, bv.s, tf, 0, 0, 0);
        #pragma unroll
        for (int r = 0; r < 4; ++r) {
          const unsigned int u = ((const unsigned int*)&xr[r])[e >> 1];
          const float xe = (e & 1) ? bf_hi(u) : bf_lo(u);
          cc4[r] += tf[r] * xe;
        }
      }
      #pragma unroll
      for (int r = 0; r < 4; ++r)
        ccl[(wave * 32 + c * 16 + col) * 17 + quad * 4 + r] = cc4[r];
    }
    // prefetch wsf NOW (R5 placement): hides under ccl write + softmax
    #pragma unroll
    for (int kt = 0; kt < 8; ++kt)
      wf8[kt] = wsf[((size_t)wave * 288 + (by << 3) + kt) * 64 + lane];
    __syncthreads();
    if (tid < 512) {                      // softmax over j per (i,b), in place
      const int i = tid >> 4, b = tid & 15;
      float cc[10];
      #pragma unroll
      for (int j = 0; j < 10; ++j) cc[j] = ccl[(j * 32 + i) * 17 + b];
      float m = cc[0];
      #pragma unroll
      for (int j = 1; j < 10; ++j) m = fmaxf(m, cc[j]);
      float den = 0.f;
      #pragma unroll
      for (int j = 0; j < 10; ++j) { cc[j] = __expf(cc[j] - m); den += cc[j]; }
      const float rd = __builtin_amdgcn_rcpf(den);
      #pragma unroll
      for (int j = 0; j < 10; ++j) ccl[(j * 32 + i) * 17 + b] = cc[j] * rd;
    }
    __syncthreads();
  }

  // Phase B: s[b,d] += (c*x) @ Ws, K=256; two independent 4-MFMA chains.
  floatx4 acc0 = {0.f, 0.f, 0.f, 0.f};
  floatx4 acc1 = {0.f, 0.f, 0.f, 0.f};
  #pragma unroll
  for (int kt = 0; kt < 8; ++kt) {
    const int il = kt * 4 + quad;         // i 0..31
    const uint4 xq = xtq[il * 17 + col];  // x[i=il][b=col]
    const float c = (round > 0) ? ccl[(wave * 32 + il) * 17 + col] : 0.1f;
    short8 af;
    unsigned int* aq = (unsigned int*)&af;
    aq[0] = pack_trunc(bf_lo(xq.x) * c, bf_hi(xq.x) * c);
    aq[1] = pack_trunc(bf_lo(xq.y) * c, bf_hi(xq.y) * c);
    aq[2] = pack_trunc(bf_lo(xq.z) * c, bf_hi(xq.z) * c);
    aq[3] = pack_trunc(bf_lo(xq.w) * c, bf_hi(xq.w) * c);
    u4s8 bw; bw.u = wf8[kt];
    if (kt & 1)
      acc1 = __builtin_amdgcn_mfma_f32_16x16x32_bf16(af, bw.s, acc1, 0, 0, 0);
    else
      acc0 = __builtin_amdgcn_mfma_f32_16x16x32_bf16(af, bw.s, acc0, 0, 0, 0);
  }
  const floatx4 acc = acc0 + acc1;
  // s_part[btile][j][b=quad*4+r][ch36][d=col]
  float* sp = s_part + ((((size_t)bx * 10 + wave) * 16 + quad * 4) * 36
                        + by) * 16 + col;
  #pragma unroll
  for (int r = 0; r < 4; ++r) sp[(size_t)r * 36 * 16] = acc[r];
}

// squash: one wave per (b,j); 9 coalesced loads (36 chunks). Unchanged R3/R5.
__global__ __launch_bounds__(256) void caps_squash(
    const float* __restrict__ s_part, float* __restrict__ vsum,
    unsigned int* __restrict__ vsbf_u, float* __restrict__ out, const int round)
{
  const int tid  = threadIdx.x;
  const int w    = tid >> 6;
  const int lane = tid & 63;
  const int bj   = blockIdx.x * 4 + w;
  const int b    = bj / 10, j = bj - b * 10;
  const int btile = b >> 4, brem = b & 15;
  const float* base = s_part + (((size_t)btile * 10 + j) * 16 + brem) * 576;
  float acc = 0.f;
  #pragma unroll
  for (int q = 0; q < 9; ++q) acc += base[q * 64 + lane];
  acc += __shfl_xor(acc, 16, 64);
  acc += __shfl_xor(acc, 32, 64);
  const float s = acc;
  float sq = s * s;
  sq += __shfl_xor(sq, 1, 16);
  sq += __shfl_xor(sq, 2, 16);
  sq += __shfl_xor(sq, 4, 16);
  sq += __shfl_xor(sq, 8, 16);
  const float coef = (sq / (1.f + sq)) * rsqrtf(sq + 1e-7f);
  const float v = coef * s;
  if (round < 2) {
    const float vprev = (lane < 16) ? vsum[bj * 16 + lane] : 0.f;
    const float vt = vprev + v;
    const float vtn = __shfl_down(vt, 1, 64);
    if (lane < 16) {
      vsum[bj * 16 + lane] = vt;
      if (!(lane & 1))
        vsbf_u[bj * 8 + (lane >> 1)] = pack_rne(vt, vtn);
    }
  } else if (lane < 16) {
    out[bj * 16 + lane] = v;
  }
}

extern "C" void kernel_launch(void* const* d_in, const int* in_sizes, int n_in,
                              void* d_out, int out_size, void* d_ws, size_t ws_size,
                              hipStream_t stream)
{
  const float* x_p = (const float*)d_in[0];   // [256][1152][8] fp32
  const float* W_p = (const float*)d_in[1];   // [10][1152][16][8] fp32

  // ws: wsf 2.95M | wcc2 2.95M | s_part 5.9M region (1.47M used + xbf 4.7M)
  uint4* wsf   = (uint4*)d_ws;
  uint4* wcc2  = wsf + 184320;
  float* s_prt = (float*)(wcc2 + 184320);               // 1474560 f used
  unsigned int* xbf = (unsigned int*)(s_prt + 1474560); // 1179648 u
  float* vsum  = s_prt + 2949120;                       // 40960 f
  unsigned int* vsbf_u = (unsigned int*)(vsum + 40960);
  float* out_p = (float*)d_out;

  caps_prep<<<dim3(720), dim3(256), 0, stream>>>(W_p, x_p, wsf, wcc2, vsum, xbf);
  for (int r = 0; r < 3; ++r) {
    caps_pass<<<dim3(576), dim3(640), 0, stream>>>(
        xbf, wsf, wcc2, (const uint4*)vsbf_u, s_prt, r);
    caps_squash<<<dim3(640), dim3(256), 0, stream>>>(
        s_prt, vsum, vsbf_u, out_p, r);
  }
}

// Round 12
// 111.055 us; speedup vs baseline: 1.6463x; 1.0036x over previous
//
#include <hip/hip_runtime.h>

#define B_N 256
#define IC_N 1152
#define J_N 10
#define D_N 16

typedef __attribute__((ext_vector_type(8))) short short8;
typedef __attribute__((ext_vector_type(4))) float floatx4;

union u4s8 { uint4 u; short8 s; };

__device__ __forceinline__ float bf_lo(unsigned int u){
  union { unsigned int i; float f; } c; c.i = u << 16; return c.f;
}
__device__ __forceinline__ float bf_hi(unsigned int u){
  union { unsigned int i; float f; } c; c.i = u & 0xffff0000u; return c.f;
}
__device__ __forceinline__ unsigned int rne16(float f){
  union { float ff; unsigned int i; } c; c.ff = f;
  return (c.i + 0x7FFFu + ((c.i >> 16) & 1u)) >> 16;
}
__device__ __forceinline__ unsigned int pack_rne(float lo, float hi){
  return rne16(lo) | (rne16(hi) << 16);
}
__device__ __forceinline__ unsigned int pack_trunc(float lo, float hi){
  union { float f; unsigned int u; } a, b; a.f = lo; b.f = hi;
  return __builtin_amdgcn_perm(b.u, a.u, 0x07060302u);
}

// prep: identical to the verified R0/R3/R5 kernel (layouts R5..R13).
__global__ __launch_bounds__(256) void caps_prep(
    const float* __restrict__ W, uint4* __restrict__ wsf,
    uint4* __restrict__ wcc2, float* __restrict__ vsum)
{
  const int tid = threadIdx.x;
  const int t0 = blockIdx.x * 256 + tid;
  if (t0 < B_N * J_N * D_N) vsum[t0] = 0.f;
  __shared__ unsigned int lw[1024];
  const int j = blockIdx.x / 72, itile = blockIdx.x % 72;
  const float4* Wt = (const float4*)(W + ((size_t)(j * IC_N + itile * 16) << 7));
  #pragma unroll
  for (int h = 0; h < 2; ++h) {
    const float4 f = Wt[h * 256 + tid];
    lw[(h * 256 + tid) * 2]     = pack_rne(f.x, f.y);
    lw[(h * 256 + tid) * 2 + 1] = pack_rne(f.z, f.w);
  }
  __syncthreads();
  {  // wsf emit
    const int ktl = tid >> 6, ln = tid & 63;
    const int base = (ktl * 4 + (ln >> 4)) * 64 + (ln & 15) * 4;
    uint4 q;
    q.x = lw[base]; q.y = lw[base + 1]; q.z = lw[base + 2]; q.w = lw[base + 3];
    wsf[((size_t)j * 288 + itile * 4 + ktl) * 64 + ln] = q;
  }
  {  // wcc2 emit
    const int e = tid >> 5, lane2 = tid & 31;
    const int il = lane2 & 15, dbase = (lane2 >> 4) * 8;
    unsigned short h[8];
    #pragma unroll
    for (int k = 0; k < 8; ++k) {
      const unsigned int u = lw[il * 64 + (dbase + k) * 4 + (e >> 1)];
      h[k] = (e & 1) ? (unsigned short)(u >> 16) : (unsigned short)(u & 0xffffu);
    }
    uint4 q;
    q.x = h[0] | ((unsigned int)h[1] << 16);
    q.y = h[2] | ((unsigned int)h[3] << 16);
    q.z = h[4] | ((unsigned int)h[5] << 16);
    q.w = h[6] | ((unsigned int)h[7] << 16);
    wcc2[(((size_t)j * 8 + e) * 72 + itile) * 32 + lane2] = q;
  }
}

// Pass: R3 backbone (32-i chunks, 576 blocks) + XCD swizzle + wf8 prefetch
// + split accumulator chains. Best measured configuration (110.2us, R5).
// Session evidence (R1..R11): device-scope sync replacements, dispatch
// fusion, intra-block pipelining, 1-wave j-serial, and traffic reductions
// all regress or are null; the barrier-convoy structure here is the
// empirically robust optimum of this decomposition.
__global__ __launch_bounds__(640, 5) void caps_pass(
    const float* __restrict__ x,
    const uint4* __restrict__ wsf, const uint4* __restrict__ wcc2,
    const uint4* __restrict__ vsbf, float* __restrict__ s_part, const int round)
{
  __shared__ float ccl[10 * 32 * 17];     // 21.8 KB
  __shared__ unsigned int xt[32 * 17 * 4];// [i 0..31][b pad17] uint4, 8.7 KB

  const int tid  = threadIdx.x;
  const int wave = tid >> 6;              // = j
  const int lane = tid & 63;
  const int quad = lane >> 4;
  const int col  = lane & 15;

  // XCD swizzle: 576 blocks = 8 xcd * 72; contiguous work per XCD.
  const int bid = blockIdx.x;
  const int wid = (bid & 7) * 72 + (bid >> 3);
  const int bx  = wid & 15;               // btile
  const int by  = wid >> 4;               // i-chunk 0..35
  const int b0  = bx << 4;
  const int i0  = by << 5;                // 32 i per block

  // ---- stage x tile: 512 threads x 2 iters, 512-B coalesced runs ----
  if (tid < 512) {
    const int b = tid >> 5, j4 = tid & 31;
    const int half = j4 & 1;
    #pragma unroll
    for (int ii = 0; ii < 2; ++ii) {
      const int i = ii * 16 + (j4 >> 1);
      const float4 v = ((const float4*)(x + ((size_t)((b0 + b) * IC_N + i0 + i) << 3)))[half];
      const int idx = ((i * 17 + b) << 2) + (half << 1);
      xt[idx]     = pack_rne(v.x, v.y);
      xt[idx + 1] = pack_rne(v.z, v.w);
    }
  }

  uint4 wf8[8];                           // phase-B W fragments, prefetched
  if (round == 0) {
    #pragma unroll
    for (int kt = 0; kt < 8; ++kt)
      wf8[kt] = wsf[((size_t)wave * 288 + (by << 3) + kt) * 64 + lane];
  }
  __syncthreads();
  const uint4* xtq = (const uint4*)xt;

  if (round > 0) {
    short8 av = {0,0,0,0,0,0,0,0};        // vsum[b=col][d=quad*8+..]; q2,3 pad
    if (quad < 2)
      av = *(const short8*)&vsbf[((size_t)(b0 + col) * J_N + wave) * 2 + quad];
    #pragma unroll
    for (int c = 0; c < 2; ++c) {         // two 16-i chunks, sequential
      uint4 bvq[8];
      #pragma unroll
      for (int e = 0; e < 8; ++e) {
        uint4 q = {0u, 0u, 0u, 0u};
        if (lane < 32)
          q = wcc2[(((size_t)wave * 8 + e) * 72 + (by * 2 + c)) * 32 + lane];
        bvq[e] = q;
      }
      uint4 xr[4];                        // x[b=quad*4+r][i=c*16+col]
      #pragma unroll
      for (int r = 0; r < 4; ++r)
        xr[r] = xtq[(c * 16 + col) * 17 + quad * 4 + r];
      floatx4 cc4 = {0.f, 0.f, 0.f, 0.f};
      #pragma unroll
      for (int e = 0; e < 8; ++e) {
        u4s8 bv; bv.u = bvq[e];
        floatx4 tf = {0.f, 0.f, 0.f, 0.f};
        tf = __builtin_amdgcn_mfma_f32_16x16x32_bf16(av, bv.s, tf, 0, 0, 0);
        #pragma unroll
        for (int r = 0; r < 4; ++r) {
          const unsigned int u = ((const unsigned int*)&xr[r])[e >> 1];
          const float xe = (e & 1) ? bf_hi(u) : bf_lo(u);
          cc4[r] += tf[r] * xe;
        }
      }
      #pragma unroll
      for (int r = 0; r < 4; ++r)
        ccl[(wave * 32 + c * 16 + col) * 17 + quad * 4 + r] = cc4[r];
    }
    // prefetch wsf NOW: latency hides under ccl write + softmax + barriers
    #pragma unroll
    for (int kt = 0; kt < 8; ++kt)
      wf8[kt] = wsf[((size_t)wave * 288 + (by << 3) + kt) * 64 + lane];
    __syncthreads();
    if (tid < 512) {                      // softmax over j per (i,b), in place
      const int i = tid >> 4, b = tid & 15;
      float cc[10];
      #pragma unroll
      for (int j = 0; j < 10; ++j) cc[j] = ccl[(j * 32 + i) * 17 + b];
      float m = cc[0];
      #pragma unroll
      for (int j = 1; j < 10; ++j) m = fmaxf(m, cc[j]);
      float den = 0.f;
      #pragma unroll
      for (int j = 0; j < 10; ++j) { cc[j] = __expf(cc[j] - m); den += cc[j]; }
      const float rd = __builtin_amdgcn_rcpf(den);
      #pragma unroll
      for (int j = 0; j < 10; ++j) ccl[(j * 32 + i) * 17 + b] = cc[j] * rd;
    }
    __syncthreads();
  }

  // Phase B: s[b,d] += (c*x) @ Ws, K=256; two independent 4-MFMA chains.
  floatx4 acc0 = {0.f, 0.f, 0.f, 0.f};
  floatx4 acc1 = {0.f, 0.f, 0.f, 0.f};
  #pragma unroll
  for (int kt = 0; kt < 8; ++kt) {
    const int il = kt * 4 + quad;         // i 0..31
    const uint4 xq = xtq[il * 17 + col];  // x[i=il][b=col]
    const float c = (round > 0) ? ccl[(wave * 32 + il) * 17 + col] : 0.1f;
    short8 af;
    unsigned int* aq = (unsigned int*)&af;
    aq[0] = pack_trunc(bf_lo(xq.x) * c, bf_hi(xq.x) * c);
    aq[1] = pack_trunc(bf_lo(xq.y) * c, bf_hi(xq.y) * c);
    aq[2] = pack_trunc(bf_lo(xq.z) * c, bf_hi(xq.z) * c);
    aq[3] = pack_trunc(bf_lo(xq.w) * c, bf_hi(xq.w) * c);
    u4s8 bw; bw.u = wf8[kt];
    if (kt & 1)
      acc1 = __builtin_amdgcn_mfma_f32_16x16x32_bf16(af, bw.s, acc1, 0, 0, 0);
    else
      acc0 = __builtin_amdgcn_mfma_f32_16x16x32_bf16(af, bw.s, acc0, 0, 0, 0);
  }
  const floatx4 acc = acc0 + acc1;
  // s_part[btile][j][b=quad*4+r][ch36][d=col]
  float* sp = s_part + ((((size_t)bx * 10 + wave) * 16 + quad * 4) * 36
                        + by) * 16 + col;
  #pragma unroll
  for (int r = 0; r < 4; ++r) sp[(size_t)r * 36 * 16] = acc[r];
}

// squash: one wave per (b,j); 9 coalesced loads (36 chunks). Verified R3/R5.
__global__ __launch_bounds__(256) void caps_squash(
    const float* __restrict__ s_part, float* __restrict__ vsum,
    unsigned int* __restrict__ vsbf_u, float* __restrict__ out, const int round)
{
  const int tid  = threadIdx.x;
  const int w    = tid >> 6;
  const int lane = tid & 63;
  const int bj   = blockIdx.x * 4 + w;
  const int b    = bj / 10, j = bj - b * 10;
  const int btile = b >> 4, brem = b & 15;
  const float* base = s_part + (((size_t)btile * 10 + j) * 16 + brem) * 576;
  float acc = 0.f;
  #pragma unroll
  for (int q = 0; q < 9; ++q) acc += base[q * 64 + lane];
  acc += __shfl_xor(acc, 16, 64);
  acc += __shfl_xor(acc, 32, 64);
  const float s = acc;
  float sq = s * s;
  sq += __shfl_xor(sq, 1, 16);
  sq += __shfl_xor(sq, 2, 16);
  sq += __shfl_xor(sq, 4, 16);
  sq += __shfl_xor(sq, 8, 16);
  const float coef = (sq / (1.f + sq)) * rsqrtf(sq + 1e-7f);
  const float v = coef * s;
  if (round < 2) {
    const float vprev = (lane < 16) ? vsum[bj * 16 + lane] : 0.f;
    const float vt = vprev + v;
    const float vtn = __shfl_down(vt, 1, 64);
    if (lane < 16) {
      vsum[bj * 16 + lane] = vt;
      if (!(lane & 1))
        vsbf_u[bj * 8 + (lane >> 1)] = pack_rne(vt, vtn);
    }
  } else if (lane < 16) {
    out[bj * 16 + lane] = v;
  }
}

extern "C" void kernel_launch(void* const* d_in, const int* in_sizes, int n_in,
                              void* d_out, int out_size, void* d_ws, size_t ws_size,
                              hipStream_t stream)
{
  const float* x_p = (const float*)d_in[0];   // [256][1152][8] fp32
  const float* W_p = (const float*)d_in[1];   // [10][1152][16][8] fp32

  uint4* wsf   = (uint4*)d_ws;
  uint4* wcc2  = wsf + 184320;
  float* s_prt = (float*)(wcc2 + 184320);             // region 2949120 f
  float* vsum  = s_prt + 2949120;                     // 40960 f
  unsigned int* vsbf_u = (unsigned int*)(vsum + 40960);
  float* out_p = (float*)d_out;

  caps_prep<<<dim3(720), dim3(256), 0, stream>>>(W_p, wsf, wcc2, vsum);
  for (int r = 0; r < 3; ++r) {
    caps_pass<<<dim3(576), dim3(640), 0, stream>>>(
        x_p, wsf, wcc2, (const uint4*)vsbf_u, s_prt, r);
    caps_squash<<<dim3(640), dim3(256), 0, stream>>>(
        s_prt, vsum, vsbf_u, out_p, r);
  }
}